// Round 1
// baseline (112.176 us; speedup 1.0000x reference)
//
#include <hip/hip_runtime.h>
#include <math.h>

#define EPS_GMO  1e-16f
#define EPS_BARY 1e-16f
#define EPS_DIV  1e-12f

// ---------------------------------------------------------------------------
// Kernel 1: gather tri[b][f][v][k] = verts[b][faces[f][v]][k]
// ---------------------------------------------------------------------------
__global__ void gather_tri_kernel(const float* __restrict__ verts,
                                  const int* __restrict__ faces,
                                  float* __restrict__ tri,
                                  int B, int F, int V)
{
    int i = blockIdx.x * blockDim.x + threadIdx.x;
    if (i >= B * F) return;
    int b = i / F;
    int f = i - b * F;
    const int* fc = faces + (size_t)f * 3;
    float* o = tri + (size_t)i * 9;
#pragma unroll
    for (int v = 0; v < 3; ++v) {
        int vi = fc[v];
        const float* vv = verts + ((size_t)b * V + vi) * 3;
        o[v * 3 + 0] = vv[0];
        o[v * 3 + 1] = vv[1];
        o[v * 3 + 2] = vv[2];
    }
}

// ---------------------------------------------------------------------------
// Exact squared point-triangle distance (Ericson), op-for-op mirror of the
// reference. contract(off) so fp32 rounding matches numpy per-op (argmin is
// sensitive to 1-ulp differences on near-ties).
// ---------------------------------------------------------------------------
__device__ float tri_sqdist(float px, float py, float pz,
                            float ax, float ay, float az,
                            float bx, float by, float bz,
                            float cx, float cy, float cz)
{
#pragma clang fp contract(off)
    float abx = bx - ax, aby = by - ay, abz = bz - az;
    float acx = cx - ax, acy = cy - ay, acz = cz - az;
    float apx = px - ax, apy = py - ay, apz = pz - az;
    float d1 = abx * apx + aby * apy + abz * apz;
    float d2 = acx * apx + acy * apy + acz * apz;
    float bpx = px - bx, bpy = py - by, bpz = pz - bz;
    float d3 = abx * bpx + aby * bpy + abz * bpz;
    float d4 = acx * bpx + acy * bpy + acz * bpz;
    float cpx_ = px - cx, cpy_ = py - cy, cpz_ = pz - cz;
    float d5 = abx * cpx_ + aby * cpy_ + abz * cpz_;
    float d6 = acx * cpx_ + acy * cpy_ + acz * cpz_;
    float va = d3 * d6 - d5 * d4;
    float vb = d5 * d2 - d1 * d6;
    float vc = d1 * d4 - d3 * d2;
    float t_ab = d1 / fmaxf(d1 - d3, EPS_DIV);
    float t_ac = d2 / fmaxf(d2 - d6, EPS_DIV);
    float t_bc = (d4 - d3) / fmaxf((d4 - d3) + (d5 - d6), EPS_DIV);
    float den = fmaxf(va + vb + vc, EPS_DIV);
    float v = vb / den;
    float w = vc / den;
    // interior closest point
    float qx = ax + v * abx + w * acx;
    float qy = ay + v * aby + w * acy;
    float qz = az + v * abz + w * acz;
    bool m_bc = (va <= 0.0f) && (d4 - d3 >= 0.0f) && (d5 - d6 >= 0.0f);
    bool m_ac = (vb <= 0.0f) && (d2 >= 0.0f) && (d6 <= 0.0f);
    bool m_ab = (vc <= 0.0f) && (d1 >= 0.0f) && (d3 <= 0.0f);
    bool m_a  = (d1 <= 0.0f) && (d2 <= 0.0f);
    bool m_b  = (d3 >= 0.0f) && (d4 <= d3);
    bool m_c  = (d6 >= 0.0f) && (d5 <= d6);
    if (m_bc) { qx = bx + t_bc * (cx - bx); qy = by + t_bc * (cy - by); qz = bz + t_bc * (cz - bz); }
    if (m_ac) { qx = ax + t_ac * acx;       qy = ay + t_ac * acy;       qz = az + t_ac * acz; }
    if (m_ab) { qx = ax + t_ab * abx;       qy = ay + t_ab * aby;       qz = az + t_ab * abz; }
    if (m_c)  { qx = cx; qy = cy; qz = cz; }
    if (m_b)  { qx = bx; qy = by; qz = bz; }
    if (m_a)  { qx = ax; qy = ay; qz = az; }
    float dx = px - qx, dy = py - qy, dz = pz - qz;
    return dx * dx + dy * dy + dz * dz;
}

// ---------------------------------------------------------------------------
// Kernel 2: per point, argmin over F faces (tie -> lowest index, matching
// jnp.argmin), then barycentric plane-projection + GMO robust value.
// One 256-thread block per (b,p).
// ---------------------------------------------------------------------------
__global__ __launch_bounds__(256) void argmin_robust_kernel(
    const float* __restrict__ points,
    const float* __restrict__ tri,
    float* __restrict__ robust_out,
    int P, int F)
{
    int blk = blockIdx.x;
    int b = blk / P;
    int p = blk - b * P;
    const float* pp = points + ((size_t)b * P + p) * 3;
    float px = pp[0], py = pp[1], pz = pp[2];

    const float* tb = tri + (size_t)b * F * 9;
    int tid = threadIdx.x;

    float best = INFINITY;
    int bestIdx = 0x7fffffff;
    for (int f = tid; f < F; f += 256) {
        const float* t = tb + (size_t)f * 9;
        float d = tri_sqdist(px, py, pz,
                             t[0], t[1], t[2],
                             t[3], t[4], t[5],
                             t[6], t[7], t[8]);
        if (d < best) { best = d; bestIdx = f; }  // strict < keeps lowest f
    }

    __shared__ float sd[256];
    __shared__ int   si[256];
    sd[tid] = best;
    si[tid] = bestIdx;
    __syncthreads();
    for (int s = 128; s > 0; s >>= 1) {
        if (tid < s) {
            float dv = sd[tid + s];
            int   iv = si[tid + s];
            if (dv < sd[tid] || (dv == sd[tid] && iv < si[tid])) {
                sd[tid] = dv; si[tid] = iv;
            }
        }
        __syncthreads();
    }

    if (tid == 0) {
#pragma clang fp contract(off)
        int f = si[0];
        const float* t = tb + (size_t)f * 9;
        float ax = t[0], ay = t[1], az = t[2];
        float bx = t[3], by = t[4], bz = t[5];
        float cx = t[6], cy = t[7], cz = t[8];
        // barycentric of plane projection (unclamped)
        float v1x = bx - ax, v1y = by - ay, v1z = bz - az;
        float v2x = cx - ax, v2y = cy - ay, v2z = cz - az;
        float nx = v1y * v2z - v1z * v2y;
        float ny = v1z * v2x - v1x * v2z;
        float nz = v1x * v2y - v1y * v2x;
        float nn = nx * nx + ny * ny + nz * nz;
        if (nn < EPS_BARY) nn = 1.0f;
        float wx = px - ax, wy = py - ay, wz = pz - az;
        // cross(v1, w)
        float c1x = v1y * wz - v1z * wy;
        float c1y = v1z * wx - v1x * wz;
        float c1z = v1x * wy - v1y * wx;
        float gamma = (c1x * nx + c1y * ny + c1z * nz) / nn;
        // cross(w, v2)
        float c2x = wy * v2z - wz * v2y;
        float c2y = wz * v2x - wx * v2z;
        float c2z = wx * v2y - wy * v2x;
        float beta = (c2x * nx + c2y * ny + c2z * nz) / nn;
        float alpha = 1.0f - beta - gamma;
        float cpx = ax * alpha + bx * beta + cx * gamma;
        float cpy = ay * alpha + by * beta + cy * gamma;
        float cpz = az * alpha + bz * beta + cz * gamma;
        float dx = cpx - px, dy = cpy - py, dz = cpz - pz;
        float sdist = dx * dx + dy * dy + dz * dz;
        // GMO with sigma = 1
        float r = sqrtf(sdist / (1.0f + sdist) + EPS_GMO);
        robust_out[blk] = r;
    }
}

// ---------------------------------------------------------------------------
// Kernel 3: deterministic fixed-order mean of N values -> out[0]
// ---------------------------------------------------------------------------
__global__ __launch_bounds__(256) void reduce_mean_kernel(
    const float* __restrict__ vals, float* __restrict__ out, int N, float inv)
{
    __shared__ float s[256];
    int tid = threadIdx.x;
    float acc = 0.0f;
    for (int i = tid; i < N; i += 256) acc += vals[i];
    s[tid] = acc;
    __syncthreads();
    for (int st = 128; st > 0; st >>= 1) {
        if (tid < st) s[tid] += s[tid + st];
        __syncthreads();
    }
    if (tid == 0) out[0] = s[0] * inv;
}

// ---------------------------------------------------------------------------
extern "C" void kernel_launch(void* const* d_in, const int* in_sizes, int n_in,
                              void* d_out, int out_size, void* d_ws, size_t ws_size,
                              hipStream_t stream)
{
    const float* points = (const float*)d_in[0];
    const float* verts  = (const float*)d_in[1];
    const int*   faces  = (const int*)d_in[2];
    float* out = (float*)d_out;

    const int B = 2;  // fixed by the reference setup
    const int P = in_sizes[0] / (B * 3);
    const int V = in_sizes[1] / (B * 3);
    const int F = in_sizes[2] / 3;

    float* tri    = (float*)d_ws;                       // B*F*9 floats
    float* robust = tri + (size_t)B * F * 9;            // B*P floats

    int nBF = B * F;
    gather_tri_kernel<<<(nBF + 255) / 256, 256, 0, stream>>>(verts, faces, tri, B, F, V);
    argmin_robust_kernel<<<B * P, 256, 0, stream>>>(points, tri, robust, P, F);
    reduce_mean_kernel<<<1, 256, 0, stream>>>(robust, out, B * P, 1.0f / (float)(B * P));
}

// Round 2
// 72.200 us; speedup vs baseline: 1.5537x; 1.5537x over previous
//
#include <hip/hip_runtime.h>
#include <math.h>

#define EPS_GMO  1e-16f
#define EPS_BARY 1e-16f
#define EPS_DIV  1e-12f
#define TPB  256
#define GPTS 2

// ---------------------------------------------------------------------------
// Kernel 1: per-face fast data: a(3), ab(3), ac(3), saa, sab, scc  (12 floats)
// ---------------------------------------------------------------------------
__global__ void gather_fdat_kernel(const float* __restrict__ verts,
                                   const int* __restrict__ faces,
                                   float* __restrict__ fdat,
                                   int B, int F, int V)
{
    int i = blockIdx.x * blockDim.x + threadIdx.x;
    if (i >= B * F) return;
    int b = i / F;
    int f = i - b * F;
    int i0 = faces[f * 3 + 0], i1 = faces[f * 3 + 1], i2 = faces[f * 3 + 2];
    const float* pa = verts + ((size_t)b * V + i0) * 3;
    const float* pb = verts + ((size_t)b * V + i1) * 3;
    const float* pc = verts + ((size_t)b * V + i2) * 3;
    float ax = pa[0], ay = pa[1], az = pa[2];
    float abx = pb[0] - ax, aby = pb[1] - ay, abz = pb[2] - az;
    float acx = pc[0] - ax, acy = pc[1] - ay, acz = pc[2] - az;
    float saa = abx * abx + aby * aby + abz * abz;
    float sab = abx * acx + aby * acy + abz * acz;
    float scc = acx * acx + acy * acy + acz * acz;
    float* o = fdat + (size_t)i * 12;
    o[0] = ax;  o[1] = ay;  o[2] = az;
    o[3] = abx; o[4] = aby; o[5] = abz;
    o[6] = acx; o[7] = acy; o[8] = acz;
    o[9] = saa; o[10] = sab; o[11] = scc;
}

// ---------------------------------------------------------------------------
// Exact squared point-triangle distance — BITWISE mirror of the reference
// (validated absmax 0.0 in round 1). Used only on pass-2 candidates.
// ---------------------------------------------------------------------------
__device__ float tri_sqdist_exact(float px, float py, float pz,
                                  float ax, float ay, float az,
                                  float bx, float by, float bz,
                                  float cx, float cy, float cz)
{
#pragma clang fp contract(off)
    float abx = bx - ax, aby = by - ay, abz = bz - az;
    float acx = cx - ax, acy = cy - ay, acz = cz - az;
    float apx = px - ax, apy = py - ay, apz = pz - az;
    float d1 = abx * apx + aby * apy + abz * apz;
    float d2 = acx * apx + acy * apy + acz * apz;
    float bpx = px - bx, bpy = py - by, bpz = pz - bz;
    float d3 = abx * bpx + aby * bpy + abz * bpz;
    float d4 = acx * bpx + acy * bpy + acz * bpz;
    float cpx_ = px - cx, cpy_ = py - cy, cpz_ = pz - cz;
    float d5 = abx * cpx_ + aby * cpy_ + abz * cpz_;
    float d6 = acx * cpx_ + acy * cpy_ + acz * cpz_;
    float va = d3 * d6 - d5 * d4;
    float vb = d5 * d2 - d1 * d6;
    float vc = d1 * d4 - d3 * d2;
    float t_ab = d1 / fmaxf(d1 - d3, EPS_DIV);
    float t_ac = d2 / fmaxf(d2 - d6, EPS_DIV);
    float t_bc = (d4 - d3) / fmaxf((d4 - d3) + (d5 - d6), EPS_DIV);
    float den = fmaxf(va + vb + vc, EPS_DIV);
    float v = vb / den;
    float w = vc / den;
    float qx = ax + v * abx + w * acx;
    float qy = ay + v * aby + w * acy;
    float qz = az + v * abz + w * acz;
    bool m_bc = (va <= 0.0f) && (d4 - d3 >= 0.0f) && (d5 - d6 >= 0.0f);
    bool m_ac = (vb <= 0.0f) && (d2 >= 0.0f) && (d6 <= 0.0f);
    bool m_ab = (vc <= 0.0f) && (d1 >= 0.0f) && (d3 <= 0.0f);
    bool m_a  = (d1 <= 0.0f) && (d2 <= 0.0f);
    bool m_b  = (d3 >= 0.0f) && (d4 <= d3);
    bool m_c  = (d6 >= 0.0f) && (d5 <= d6);
    if (m_bc) { qx = bx + t_bc * (cx - bx); qy = by + t_bc * (cy - by); qz = bz + t_bc * (cz - bz); }
    if (m_ac) { qx = ax + t_ac * acx;       qy = ay + t_ac * acy;       qz = az + t_ac * acz; }
    if (m_ab) { qx = ax + t_ab * abx;       qy = ay + t_ab * aby;       qz = az + t_ab * abz; }
    if (m_c)  { qx = cx; qy = cy; qz = cz; }
    if (m_b)  { qx = bx; qy = by; qz = bz; }
    if (m_a)  { qx = ax; qy = ay; qz = az; }
    float dx = px - qx, dy = py - qy, dz = pz - qz;
    return dx * dx + dy * dy + dz * dz;
}

// ---------------------------------------------------------------------------
// Main kernel: GPTS points per block. Pass 1 = fast screen (FMA + rcp),
// pass 2 = exact-mirror argmin over candidates, then exact barycentric + GMO.
// ---------------------------------------------------------------------------
__global__ __launch_bounds__(TPB) void p2s_main_kernel(
    const float* __restrict__ points,
    const float* __restrict__ verts,
    const int* __restrict__ faces,
    const float* __restrict__ fdat,
    float* __restrict__ robust_out,
    int P, int V, int F, int npts)
{
    extern __shared__ unsigned short dstore[];   // [GPTS][F] bf16-truncated fast d
    __shared__ float sd[TPB];
    __shared__ int   si[TPB];
    __shared__ float sT[GPTS];
    __shared__ int   sFace[GPTS];

    const int tid = threadIdx.x;
    const int gp0 = blockIdx.x * GPTS;
    const int b   = gp0 / P;   // P % GPTS == 0, block never straddles batches

    float px[GPTS], py[GPTS], pz[GPTS];
#pragma unroll
    for (int g = 0; g < GPTS; ++g) {
        int gp = gp0 + g; if (gp >= npts) gp = npts - 1;
        const float* pp = points + (size_t)gp * 3;
        px[g] = pp[0]; py[g] = pp[1]; pz[g] = pp[2];
    }

    const float* fb = fdat + (size_t)b * F * 12;

    // ---------------- pass 1: fast distances ----------------
    float best[GPTS];
#pragma unroll
    for (int g = 0; g < GPTS; ++g) best[g] = INFINITY;

    for (int f = tid; f < F; f += TPB) {
        const float* fd = fb + (size_t)f * 12;
        float4 q0 = *(const float4*)(fd + 0);
        float4 q1 = *(const float4*)(fd + 4);
        float4 q2 = *(const float4*)(fd + 8);
        float ax = q0.x, ay = q0.y, az = q0.z;
        float abx = q0.w, aby = q1.x, abz = q1.y;
        float acx = q1.z, acy = q1.w, acz = q2.x;
        float saa = q2.y, sab = q2.z, scc = q2.w;
        float cbb = saa - 2.0f * sab + scc;          // |c-b|^2
        float rsaa = __builtin_amdgcn_rcpf(fmaxf(saa, 1e-30f));
        float rscc = __builtin_amdgcn_rcpf(fmaxf(scc, 1e-30f));
        float rcbb = __builtin_amdgcn_rcpf(fmaxf(cbb, 1e-30f));
#pragma unroll
        for (int g = 0; g < GPTS; ++g) {
            float apx = px[g] - ax, apy = py[g] - ay, apz = pz[g] - az;
            float d1 = apx * abx + apy * aby + apz * abz;
            float d2 = apx * acx + apy * acy + apz * acz;
            float d3 = d1 - saa, d4 = d2 - sab, d5 = d1 - sab, d6 = d2 - scc;
            float e1 = d4 - d3, e2 = d5 - d6;
            float va = d3 * d6 - d5 * d4;
            float vb = d5 * d2 - d1 * d6;
            float vc = d1 * d4 - d3 * d2;
            float rden = __builtin_amdgcn_rcpf(fmaxf(va + vb + vc, EPS_DIV));
            float t_ab = d1 * rsaa, t_ac = d2 * rscc, t_bc = e1 * rcbb;
            bool m_bc = (va <= 0.0f) & (e1 >= 0.0f) & (e2 >= 0.0f);
            bool m_ac = (vb <= 0.0f) & (d2 >= 0.0f) & (d6 <= 0.0f);
            bool m_ab = (vc <= 0.0f) & (d1 >= 0.0f) & (d3 <= 0.0f);
            bool m_a  = (d1 <= 0.0f) & (d2 <= 0.0f);
            bool m_b  = (d3 >= 0.0f) & (e1 <= 0.0f);
            bool m_c  = (d6 >= 0.0f) & (e2 <= 0.0f);
            // priority (last overwrite wins in ref): m_a > m_b > m_c > m_ab > m_ac > m_bc > interior
            float v = m_a ? 0.0f : m_b ? 1.0f : m_c ? 0.0f : m_ab ? t_ab
                    : m_ac ? 0.0f : m_bc ? (1.0f - t_bc) : vb * rden;
            float w = m_a ? 0.0f : m_b ? 0.0f : m_c ? 1.0f : m_ab ? 0.0f
                    : m_ac ? t_ac : m_bc ? t_bc : vc * rden;
            float cvx = apx - v * abx - w * acx;
            float cvy = apy - v * aby - w * acy;
            float cvz = apz - v * abz - w * acz;
            float d = cvx * cvx + cvy * cvy + cvz * cvz;
            dstore[g * F + f] = (unsigned short)(__float_as_uint(d) >> 16); // trunc -> <= d
            best[g] = fminf(best[g], d);   // v_min: NaN (degenerate face) excluded
        }
    }

    // ---------------- reduce per-point fast min, build thresholds ----------------
#pragma unroll
    for (int g = 0; g < GPTS; ++g) {
        sd[tid] = best[g];
        __syncthreads();
        for (int s = TPB / 2; s > 0; s >>= 1) {
            if (tid < s) sd[tid] = fminf(sd[tid], sd[tid + s]);
            __syncthreads();
        }
        if (tid == 0) sT[g] = sd[0] + (1e-6f + 4e-3f * sd[0]);
        __syncthreads();
    }

    // ---------------- pass 2: exact-mirror argmin over candidates ----------------
    float bestE[GPTS]; int bestI[GPTS]; float Tg[GPTS];
#pragma unroll
    for (int g = 0; g < GPTS; ++g) {
        bestE[g] = INFINITY; bestI[g] = 0x7fffffff; Tg[g] = sT[g];
    }

    for (int f = tid; f < F; f += TPB) {
        bool c0 = __uint_as_float((unsigned)dstore[f] << 16) <= Tg[0];
        bool c1 = __uint_as_float((unsigned)dstore[F + f] << 16) <= Tg[1];
        if (c0 | c1) {
            int i0 = faces[f * 3 + 0], i1 = faces[f * 3 + 1], i2 = faces[f * 3 + 2];
            const float* pa = verts + ((size_t)b * V + i0) * 3;
            const float* pbv = verts + ((size_t)b * V + i1) * 3;
            const float* pc = verts + ((size_t)b * V + i2) * 3;
            float ax = pa[0], ay = pa[1], az = pa[2];
            float bx = pbv[0], by = pbv[1], bz = pbv[2];
            float cx = pc[0], cy = pc[1], cz = pc[2];
            if (c0) {
                float de = tri_sqdist_exact(px[0], py[0], pz[0], ax, ay, az, bx, by, bz, cx, cy, cz);
                if (de < bestE[0]) { bestE[0] = de; bestI[0] = f; }
            }
            if (c1) {
                float de = tri_sqdist_exact(px[1], py[1], pz[1], ax, ay, az, bx, by, bz, cx, cy, cz);
                if (de < bestE[1]) { bestE[1] = de; bestI[1] = f; }
            }
        }
    }

#pragma unroll
    for (int g = 0; g < GPTS; ++g) {
        sd[tid] = bestE[g]; si[tid] = bestI[g];
        __syncthreads();
        for (int s = TPB / 2; s > 0; s >>= 1) {
            if (tid < s) {
                float dv = sd[tid + s]; int iv = si[tid + s];
                if (dv < sd[tid] || (dv == sd[tid] && iv < si[tid])) { sd[tid] = dv; si[tid] = iv; }
            }
            __syncthreads();
        }
        if (tid == 0) sFace[g] = si[0];
        __syncthreads();
    }

    // ---------------- final: exact barycentric + GMO (mirror) ----------------
    if (tid < GPTS) {
#pragma clang fp contract(off)
        int g = tid;
        int gp = gp0 + g;
        if (gp < npts) {
            int f = sFace[g];
            int i0 = faces[f * 3 + 0], i1 = faces[f * 3 + 1], i2 = faces[f * 3 + 2];
            const float* pa = verts + ((size_t)b * V + i0) * 3;
            const float* pbv = verts + ((size_t)b * V + i1) * 3;
            const float* pc = verts + ((size_t)b * V + i2) * 3;
            float ax = pa[0], ay = pa[1], az = pa[2];
            float bx = pbv[0], by = pbv[1], bz = pbv[2];
            float cx = pc[0], cy = pc[1], cz = pc[2];
            float Px = px[g], Py = py[g], Pz = pz[g];
            float v1x = bx - ax, v1y = by - ay, v1z = bz - az;
            float v2x = cx - ax, v2y = cy - ay, v2z = cz - az;
            float nx = v1y * v2z - v1z * v2y;
            float ny = v1z * v2x - v1x * v2z;
            float nz = v1x * v2y - v1y * v2x;
            float nn = nx * nx + ny * ny + nz * nz;
            if (nn < EPS_BARY) nn = 1.0f;
            float wx = Px - ax, wy = Py - ay, wz = Pz - az;
            float c1x = v1y * wz - v1z * wy;
            float c1y = v1z * wx - v1x * wz;
            float c1z = v1x * wy - v1y * wx;
            float gamma = (c1x * nx + c1y * ny + c1z * nz) / nn;
            float c2x = wy * v2z - wz * v2y;
            float c2y = wz * v2x - wx * v2z;
            float c2z = wx * v2y - wy * v2x;
            float beta = (c2x * nx + c2y * ny + c2z * nz) / nn;
            float alpha = 1.0f - beta - gamma;
            float cpx = ax * alpha + bx * beta + cx * gamma;
            float cpy = ay * alpha + by * beta + cy * gamma;
            float cpz = az * alpha + bz * beta + cz * gamma;
            float dx = cpx - Px, dy = cpy - Py, dz = cpz - Pz;
            float sdist = dx * dx + dy * dy + dz * dz;
            float r = sqrtf(sdist / (1.0f + sdist) + EPS_GMO);
            robust_out[gp] = r;
        }
    }
}

// ---------------------------------------------------------------------------
// Kernel 3: deterministic fixed-order mean of N values -> out[0]
// ---------------------------------------------------------------------------
__global__ __launch_bounds__(TPB) void reduce_mean_kernel(
    const float* __restrict__ vals, float* __restrict__ out, int N, float inv)
{
    __shared__ float s[TPB];
    int tid = threadIdx.x;
    float acc = 0.0f;
    for (int i = tid; i < N; i += TPB) acc += vals[i];
    s[tid] = acc;
    __syncthreads();
    for (int st = TPB / 2; st > 0; st >>= 1) {
        if (tid < st) s[tid] += s[tid + st];
        __syncthreads();
    }
    if (tid == 0) out[0] = s[0] * inv;
}

// ---------------------------------------------------------------------------
extern "C" void kernel_launch(void* const* d_in, const int* in_sizes, int n_in,
                              void* d_out, int out_size, void* d_ws, size_t ws_size,
                              hipStream_t stream)
{
    const float* points = (const float*)d_in[0];
    const float* verts  = (const float*)d_in[1];
    const int*   faces  = (const int*)d_in[2];
    float* out = (float*)d_out;

    const int B = 2;  // fixed by the reference setup
    const int P = in_sizes[0] / (B * 3);
    const int V = in_sizes[1] / (B * 3);
    const int F = in_sizes[2] / 3;
    const int npts = B * P;

    float* fdat   = (float*)d_ws;                    // B*F*12 floats
    float* robust = fdat + (size_t)B * F * 12;       // npts floats

    int nBF = B * F;
    gather_fdat_kernel<<<(nBF + TPB - 1) / TPB, TPB, 0, stream>>>(verts, faces, fdat, B, F, V);

    int nBlocks = (npts + GPTS - 1) / GPTS;
    size_t dynLds = (size_t)GPTS * F * sizeof(unsigned short);
    p2s_main_kernel<<<nBlocks, TPB, dynLds, stream>>>(points, verts, faces, fdat, robust, P, V, F, npts);

    reduce_mean_kernel<<<1, TPB, 0, stream>>>(robust, out, npts, 1.0f / (float)npts);
}